// Round 11
// baseline (384.472 us; speedup 1.0000x reference)
//
#include <hip/hip_runtime.h>
#include <hip/hip_bf16.h>
#include <stdint.h>

// Problem: feats[8,1024,32,32]f32, conv_w[256,1024]f32, conv_b[256]f32,
// codebook[16384,256]f32 -> z_q[8,256,32,32]f32 (2097152) + loss scalar.
//
// Round-22 design: TWO kernels. Evidence: non-gemm2 time has been a constant
// ~110-119 us across r11-r21 regardless of how much work prep/gemm1/final do
// (r21 deleted the featsT+zb round-trips -> no change). Ideal memory time for
// those kernels is ~25 us -> the cost is per-launch fixed overhead + latency-
// exposed small-grid kernels (k_final ran 1 wave/SIMD). So: minimize launches.
//  - K1 k_fused1 (776 blocks): [0,512) gemm1 BM=16/BN=256 (block owns full
//    e-range: A read once (32MB), B staged straight from conv_w f32, zsq via
//    LDS reduce - no atomics, no init precursor); [512,768) cbs8 build;
//    [768,776) best/cnt/lossw init. All outputs feed only K2 - no races.
//  - K2 k_gemm2 (i8 MFMA + int fold, unchanged main) + last-block-per-column
//    tail: atomicAdd(cnt[by]) after atomicMax; 32nd block decodes winners
//    (atomic reads), accumulates loss, gathers 128 codebook rows -> out.
//    k_final eliminated; its latency hides inside K2's dispatch.

typedef float f32x4 __attribute__((ext_vector_type(4)));
typedef int i32x4 __attribute__((ext_vector_type(4)));
typedef int i32x16 __attribute__((ext_vector_type(16)));
typedef short s16x8 __attribute__((ext_vector_type(8)));

__device__ __forceinline__ void gl2lds16(const void* g, void* l) {
  __builtin_amdgcn_global_load_lds(
      (const __attribute__((address_space(1))) void*)g,
      (__attribute__((address_space(3))) void*)l, 16, 0, 0);
}

__device__ __forceinline__ unsigned short f2bf(float f) {
  unsigned u = __float_as_uint(f);
  u = u + 0x7FFFu + ((u >> 16) & 1u);
  return (unsigned short)(u >> 16);
}

__device__ __forceinline__ ushort4 cvt4(float4 v) {
  ushort4 o;
  o.x = f2bf(v.x); o.y = f2bf(v.y); o.z = f2bf(v.z); o.w = f2bf(v.w);
  return o;
}

// K1: fused gemm1 + cbs8 build + inits. 776 blocks x 256 thr.
// [0,512):   gemm1 tile: 16 i-rows x 256 e (full), K=1024, BK=128.
//            A staged from feats f32 (c-rows, lanes along s; same fragment
//            layout as the proven r21 path, 16-row variant). B staged from
//            conv_w f32 (float4 + cvt4, [kp][e][16B]). 4 waves, each wave
//            16i x 64e: acc[4] f32x4. zsq[i] computed in-block via LDS.
// [512,768): codebook -> cbs8 (i8, scale 127*16384) in 32x32x32 A-fragment
//            order, jt = blk-512 (proven r19 mapping).
// [768,776): best = INT_MIN; block 768 also cnt[64] = 0, lossw = 0.
__global__ __launch_bounds__(256, 2)
void k_fused1(const float* __restrict__ cbk, const float* __restrict__ Wsrc,
              const float* __restrict__ bias, const float* __restrict__ feats,
              signed char* __restrict__ cbs8, signed char* __restrict__ z8,
              float* __restrict__ zsq, int* __restrict__ best,
              int* __restrict__ cnt, float* __restrict__ lossw) {
  __shared__ __align__(16) uint8_t ldsA[4096];   // [kp 16][s 16][16B]
  __shared__ __align__(16) uint8_t ldsB[65536];  // [kp 16][e 256][16B]
  __shared__ float zs[4][16];
  const int blk = blockIdx.x, t = threadIdx.x;
  if (blk >= 512) {
    if (blk < 768) {
      int jt = blk - 512;
      #pragma unroll
      for (int lp = 0; lp < 4; ++lp) {
        int fl = lp * 256 + t;  // [0,1024): [ks 8][fr 2][lane 64]
        int ks = fl >> 7, fr = (fl >> 6) & 1, lane = fl & 63;
        int j = jt * 64 + fr * 32 + (lane & 31);
        int k = ks * 32 + (lane >> 5) * 16;
        const float* src = cbk + (size_t)j * 256 + k;
        int w4[4];
        #pragma unroll
        for (int q4 = 0; q4 < 4; ++q4) {
          float4 v = *(const float4*)(src + q4 * 4);
          int b0 = __float2int_rn(v.x * 2080768.0f);  // 127*16384
          int b1 = __float2int_rn(v.y * 2080768.0f);
          int b2 = __float2int_rn(v.z * 2080768.0f);
          int b3 = __float2int_rn(v.w * 2080768.0f);
          w4[q4] = (b0 & 255) | ((b1 & 255) << 8) | ((b2 & 255) << 16) | ((b3 & 255) << 24);
        }
        *(int4*)(cbs8 + (size_t)jt * 16384 + (size_t)fl * 16) =
            make_int4(w4[0], w4[1], w4[2], w4[3]);
      }
    } else {
      int bb = blk - 768;
      #pragma unroll
      for (int k = 0; k < 4; ++k)
        best[bb * 1024 + k * 256 + t] = (int)0x80000000;
      if (bb == 0) {
        if (t < 2) ((int*)lossw)[t] = 0;
        if (t < 64) cnt[t] = 0;
      }
    }
    return;
  }
  // ---- gemm1 block: rows ib..ib+15, all 256 e ----
  const int w = t >> 6, l = t & 63, l15 = l & 15, q = l >> 4;
  const int ib = blk * 16;
  const int b1024 = (ib >> 10) << 10, s0 = ib & 1023;
  const int sA = t & 15, cg = t >> 4;  // staging coords
  f32x4 acc[4] = {};
  for (int kt = 0; kt < 8; ++kt) {
    int c0 = kt * 128;
    __syncthreads();
    // A: feats f32 -> bf16, layout [kp=c>>3][s][16B] (8 c per 16B packet)
    #pragma unroll
    for (int r = 0; r < 2; ++r) {
      int c = cg * 8 + r * 4;
      const float* src = feats + (size_t)(b1024 + c0 + c) * 1024 + s0 + sA;
      float4 v;
      v.x = src[0]; v.y = src[1024]; v.z = src[2048]; v.w = src[3072];
      *(ushort4*)(ldsA + ((c >> 3) * 16 + sA) * 16 + (c & 4) * 2) = cvt4(v);
    }
    // B: conv_w f32 -> bf16, layout [kp][e][16B]
    #pragma unroll
    for (int r = 0; r < 32; ++r) {
      int P = t + 256 * r;  // e = P&255, g = P>>8 (c-offset 4g)
      int e = P & 255, g = P >> 8;
      float4 v = *(const float4*)(Wsrc + (size_t)e * 1024 + c0 + g * 4);
      *(ushort4*)(ldsB + ((g >> 1) * 256 + e) * 16 + (g & 1) * 8) = cvt4(v);
    }
    __syncthreads();
    #pragma unroll
    for (int s = 0; s < 4; ++s) {
      s16x8 a = *(const s16x8*)(ldsA + ((s * 4 + q) * 16 + l15) * 16);
      s16x8 b[4];
      #pragma unroll
      for (int fe = 0; fe < 4; ++fe)
        b[fe] = *(const s16x8*)(ldsB + ((s * 4 + q) * 256 + w * 64 + fe * 16 + l15) * 16);
      #pragma unroll
      for (int fe = 0; fe < 4; ++fe)
        acc[fe] = __builtin_amdgcn_mfma_f32_16x16x32_bf16(a, b[fe], acc[fe], 0, 0, 0);
    }
  }
  // epilogue: z8 + zsq (LDS reduce, no atomics)
  float zv[4][4];
  #pragma unroll
  for (int fe = 0; fe < 4; ++fe) {
    int e = w * 64 + fe * 16 + l15;
    float bv = bias[e];
    #pragma unroll
    for (int r = 0; r < 4; ++r) {
      float zf = acc[fe][r] + bv;
      zv[fe][r] = zf;
      int i = ib + q * 4 + r;
      int qv = __float2int_rn(zf * 16.0f);
      qv = qv > 127 ? 127 : (qv < -127 ? -127 : qv);
      z8[(size_t)i * 256 + e] = (signed char)qv;
    }
  }
  #pragma unroll
  for (int r = 0; r < 4; ++r) {
    float p = zv[0][r] * zv[0][r] + zv[1][r] * zv[1][r]
            + zv[2][r] * zv[2][r] + zv[3][r] * zv[3][r];
    p += __shfl_xor(p, 1, 64);
    p += __shfl_xor(p, 2, 64);
    p += __shfl_xor(p, 4, 64);
    p += __shfl_xor(p, 8, 64);
    if (l15 == 0) zs[w][q * 4 + r] = p;  // per-wave slot, no race
  }
  __syncthreads();
  if (t < 16) zsq[ib + t] = zs[0][t] + zs[1][t] + zs[2][t] + zs[3][t];
}

// K2: GEMM2 + argmax in INT8 (unchanged main: 32x32x32 j-stream, wave tile
// 64j x 128i, acc 128 AGPR, int fold p=(acc<<9)+(511-slot), v_max3) + TAIL:
// after atomicMax, atomicAdd(cnt[by]); the 32nd (last) block per ib-column
// decodes winners via device-scope atomic reads, accumulates the loss, and
// gathers its 128 codebook rows -> out (k_final's job, fused).
__global__ __launch_bounds__(256, 2)
void k_gemm2(const signed char* __restrict__ cbs8, const signed char* __restrict__ z8,
             int* __restrict__ best, int* __restrict__ cnt,
             const float* __restrict__ zsq, const float* __restrict__ cbk,
             float* __restrict__ lossw, float* __restrict__ out) {
  __shared__ __align__(16) uint8_t smem[32896];  // ldsB (32KB) / tail tile[32][257]
  __shared__ int csh[4][128];
  __shared__ int lidx[128];
  __shared__ float ps[4];
  __shared__ int tailflag;
  uint8_t* ldsB = smem;
  const int t = threadIdx.x, w = t >> 6, l = t & 63;
  const int l31 = l & 31, h = l >> 5;
  const int ib = blockIdx.y * 128;
  // stage z8 tile: packet P -> i = P&127, kseg = P>>7 (16B per packet)
  #pragma unroll
  for (int r = 0; r < 8; ++r) {
    int P = t + 256 * r;
    gl2lds16(z8 + (size_t)(ib + (P & 127)) * 256 + (P >> 7) * 16, ldsB + P * 16);
  }
  int ibest[4];
  #pragma unroll
  for (int fc = 0; fc < 4; ++fc) ibest[fc] = (int)0x80000000;
  __syncthreads();
  const uint8_t* bbase = ldsB + (h * 128 + l31) * 16;  // + ks*4096 + fc*512
  #pragma unroll 1
  for (int js = 0; js < 2; ++js) {
    const int jtile = blockIdx.x * 8 + js * 4 + w;  // 64-j tile index
    const uint8_t* abase = (const uint8_t*)cbs8 + (size_t)jtile * 16384 + l * 16;
    i32x16 acc[2][4] = {};  // [fr j-half][fc i-quarter]
    #pragma unroll 2
    for (int ks = 0; ks < 8; ++ks) {
      i32x4 a0 = *(const i32x4*)(abase + (ks * 2) * 1024);
      i32x4 a1 = *(const i32x4*)(abase + (ks * 2 + 1) * 1024);
      i32x4 b0 = *(const i32x4*)(bbase + ks * 4096);
      i32x4 b1 = *(const i32x4*)(bbase + ks * 4096 + 512);
      i32x4 b2 = *(const i32x4*)(bbase + ks * 4096 + 1024);
      i32x4 b3 = *(const i32x4*)(bbase + ks * 4096 + 1536);
      acc[0][0] = __builtin_amdgcn_mfma_i32_32x32x32_i8(a0, b0, acc[0][0], 0, 0, 0);
      acc[1][0] = __builtin_amdgcn_mfma_i32_32x32x32_i8(a1, b0, acc[1][0], 0, 0, 0);
      acc[0][1] = __builtin_amdgcn_mfma_i32_32x32x32_i8(a0, b1, acc[0][1], 0, 0, 0);
      acc[1][1] = __builtin_amdgcn_mfma_i32_32x32x32_i8(a1, b1, acc[1][1], 0, 0, 0);
      acc[0][2] = __builtin_amdgcn_mfma_i32_32x32x32_i8(a0, b2, acc[0][2], 0, 0, 0);
      acc[1][2] = __builtin_amdgcn_mfma_i32_32x32x32_i8(a1, b2, acc[1][2], 0, 0, 0);
      acc[0][3] = __builtin_amdgcn_mfma_i32_32x32x32_i8(a0, b3, acc[0][3], 0, 0, 0);
      acc[1][3] = __builtin_amdgcn_mfma_i32_32x32x32_i8(a1, b3, acc[1][3], 0, 0, 0);
    }
    // int fold: slot = js*256 + fr*32 + ((rg&3)+8*(rg>>2)); code = 511-slot
    const int cbase = 511 - js * 256;
    #pragma unroll
    for (int fc = 0; fc < 4; ++fc) {
      int bb = ibest[fc];
      #pragma unroll
      for (int fr = 0; fr < 2; ++fr) {
        const int c1 = cbase - fr * 32;
        #pragma unroll
        for (int rg = 0; rg < 16; rg += 2) {
          int c0 = c1 - ((rg & 3) + 8 * (rg >> 2));  // rg even; rg+1 -> c0-1
          int p0 = (int)(((unsigned)acc[fr][fc][rg] << 9) + (unsigned)c0);
          int p1 = (int)(((unsigned)acc[fr][fc][rg + 1] << 9) + (unsigned)(c0 - 1));
          bb = max(max(p0, p1), bb);  // v_max3_i32
        }
      }
      ibest[fc] = bb;
    }
  }
  // decode winner per fc -> global float encode; reduce over h; atomicMax.
  const float inv = 1.0f / 33292288.0f;  // 1/(16*127*16384)
  const int jbase = blockIdx.x * 512 + w * 64 + 4 * h;
  #pragma unroll
  for (int fc = 0; fc < 4; ++fc) {
    int p = ibest[fc];
    int accw = p >> 9;               // exact (code >= 0)
    int loc = 511 - (p & 511);       // js*256 + fr*32 + joff
    int j = jbase + loc;
    float s = fmaf((float)accw, inv, 3.0f);
    int gb = (int)(((unsigned)__float_as_int(s) << 14) + (unsigned)(16383 - j));
    int bb = max(gb, __shfl_xor(gb, 32, 64));
    if (l < 32) csh[w][fc * 32 + l31] = bb;
  }
  __syncthreads();
  if (t < 128) {
    int m0 = max(max(csh[0][t], csh[1][t]), max(csh[2][t], csh[3][t]));
    atomicMax(&best[ib + t], m0);
  }
  // ---- tail: last block of this ib-column finalizes the 128 rows ----
  __threadfence();  // my atomicMax visible before the counter bump
  __syncthreads();
  if (t == 0) tailflag = (atomicAdd(&cnt[blockIdx.y], 1) == 31) ? 1 : 0;
  __syncthreads();
  if (!tailflag) return;
  float d = 0.0f;
  if (t < 128) {
    int bv = atomicMax(&best[ib + t], (int)0x80000000);  // coherent read
    lidx[t] = 16383 - (bv & 0x3FFF);
    d = zsq[ib + t] - (float)(bv >> 14) * (1.0f / 1048576.0f);  // 2*score
  }
  d += __shfl_down(d, 32, 64);
  d += __shfl_down(d, 16, 64);
  d += __shfl_down(d, 8, 64);
  d += __shfl_down(d, 4, 64);
  d += __shfl_down(d, 2, 64);
  d += __shfl_down(d, 1, 64);
  if (l == 0) ps[w] = d;
  __syncthreads();
  if (t == 0) {
    atomicAdd(lossw, ps[0] + ps[1] + ps[2] + ps[3]);
    __threadfence();
    int c2 = atomicAdd((int*)lossw + 1, 1);
    if (c2 == 63) {
      __threadfence();
      float total = atomicAdd(lossw, 0.0f);
      out[2097152] = 1.25f * total * (1.0f / 2097152.0f);
    }
  }
  // gather 128 rows in 4 passes of 32 (tile aliases ldsB; synced)
  float (*tile)[257] = (float (*)[257])smem;
  const int bmaj = ib >> 10, s0g = ib & 1023;
  #pragma unroll 1
  for (int p = 0; p < 4; ++p) {
    __syncthreads();
    #pragma unroll
    for (int rr = 0; rr < 8; ++rr) {
      int r = w * 8 + rr;
      const float* src = cbk + (size_t)lidx[p * 32 + r] * 256;
      #pragma unroll
      for (int k = 0; k < 4; ++k)
        tile[r][l + 64 * k] = src[l + 64 * k];
    }
    __syncthreads();
    int sl = t & 31, eg = t >> 5;  // eg 0..7
    size_t ob = (size_t)bmaj * 262144 + s0g + p * 32 + sl;
    #pragma unroll
    for (int k = 0; k < 32; ++k) {
      int e = eg + 8 * k;
      out[ob + (size_t)e * 1024] = tile[sl][e];
    }
  }
}

extern "C" void kernel_launch(void* const* d_in, const int* in_sizes, int n_in,
                              void* d_out, int out_size, void* d_ws, size_t ws_size,
                              hipStream_t stream) {
  const float* feats  = (const float*)d_in[0];
  const float* conv_w = (const float*)d_in[1];
  const float* conv_b = (const float*)d_in[2];
  const float* cbk    = (const float*)d_in[3];
  float* out = (float*)d_out;
  char* ws = (char*)d_ws;
  // workspace layout (bytes), ~6.4 MB total
  signed char* cbs8  = (signed char*)(ws);                 //  4,194,304
  signed char* z8    = (signed char*)(ws + 4194304);       //  2,097,152
  int*         best  = (int*)(ws + 6291456);               //     32,768
  float*       zsq   = (float*)(ws + 6324224);             //     32,768
  int*         cnt   = (int*)(ws + 6356992);               //        256
  float*       lossw = (float*)(ws + 6357248);             //        256

  k_fused1<<<776, 256, 0, stream>>>(cbk, conv_w, conv_b, feats,
                                    cbs8, z8, zsq, best, cnt, lossw);
  k_gemm2<<<dim3(32, 64), 256, 0, stream>>>(cbs8, z8, best, cnt,
                                            zsq, cbk, lossw, out);
}